// Round 10
// baseline (263.928 us; speedup 1.0000x reference)
//
#include <hip/hip_runtime.h>
#include <hip/hip_bf16.h>

typedef __attribute__((ext_vector_type(4))) float f32x4;
typedef __attribute__((ext_vector_type(8))) short bf16x8;
typedef __attribute__((ext_vector_type(4))) short short4v;

__device__ __forceinline__ short f2bf(float f) {
  union { float f; unsigned u; } x; x.f = f;
  unsigned r = x.u + 0x7fffu + ((x.u >> 16) & 1u);
  return (short)(r >> 16);
}

__device__ __forceinline__ float fexp2(float x) {
#if __has_builtin(__builtin_amdgcn_exp2f)
  return __builtin_amdgcn_exp2f(x);
#else
  return exp2f(x);
#endif
}

#define WAITVM(n) { asm volatile("s_waitcnt vmcnt(" #n ")" ::: "memory"); __builtin_amdgcn_sched_barrier(0); }
#define BARRIER() { __builtin_amdgcn_sched_barrier(0); asm volatile("s_barrier" ::: "memory"); __builtin_amdgcn_sched_barrier(0); }
#define GLD16(g, l) __builtin_amdgcn_global_load_lds((const __attribute__((address_space(1))) void*)(g), (__attribute__((address_space(3))) void*)(l), 16, 0, 0)

// Q pre-scale folded into the QKV GEMM epilogue: 1/sqrt(dh) * log2(e)
#define QSC (0.08838834764831845f * 1.4426950408889634f)

// ---------------- cast f32 -> bf16 (RNE), 4 elems/thread ----------------
__global__ __launch_bounds__(256) void cast_kernel(const float* __restrict__ in,
                                                   short* __restrict__ out, int n4) {
  int i = blockIdx.x * 256 + threadIdx.x;
  if (i < n4) {
    const float4 v = reinterpret_cast<const float4*>(in)[i];
    short4v s;
    s.x = f2bf(v.x); s.y = f2bf(v.y); s.z = f2bf(v.z); s.w = f2bf(v.w);
    reinterpret_cast<short4v*>(out)[i] = s;
  }
}

// all 4 weights in one dispatch; Wq/Wk/Wv -> contiguous qkv buffer, Wo -> wo
__global__ __launch_bounds__(256) void cast_w_kernel(const float* __restrict__ w0,
                                                     const float* __restrict__ w1,
                                                     const float* __restrict__ w2,
                                                     const float* __restrict__ w3,
                                                     short* __restrict__ qkv,
                                                     short* __restrict__ wo) {
  const int y = blockIdx.y;
  const float* in = (y == 0) ? w0 : (y == 1) ? w1 : (y == 2) ? w2 : w3;
  short* out = (y < 3) ? (qkv + (long)y * 4194304) : wo;
  const int i = blockIdx.x * 256 + threadIdx.x;
  const float4 v = reinterpret_cast<const float4*>(in)[i];
  short4v s;
  s.x = f2bf(v.x); s.y = f2bf(v.y); s.z = f2bf(v.z); s.w = f2bf(v.w);
  reinterpret_cast<short4v*>(out)[i] = s;
}

// ---------------- fused QKV GEMM: 128x384 tile, BK=64, 3-phase counted-vmcnt ----------------
// (unchanged from round 9; race proof in round-8 comments)
__global__ __launch_bounds__(512, 2) void gemm_qkv8(const short* __restrict__ A,
                                                    const short* __restrict__ W,
                                                    short* __restrict__ Qo,
                                                    short* __restrict__ Ko,
                                                    short* __restrict__ Vt) {
  __shared__ __align__(1024) char lds[131072];   // 2 buf x 64KB
  const int tid  = threadIdx.x;
  const int lane = tid & 63;
  const int w    = tid >> 6;
  const int wm   = w >> 2, wn = w & 3;
  const int l16  = lane & 15, g = lane >> 4;
  const int K    = 2048;

  int id = (int)blockIdx.x;
  id = (id & 7) * 64 + (id >> 3);
  const int mb = id & 31, nb = id >> 5;
  const long m0 = (long)mb * 128, n0 = (long)nb * 384;

  const int srow = lane >> 3;
  const int scol = ((lane & 7) ^ srow) * 8;
  const int csw  = (l16 & 7) << 4;

  f32x4 acc[4][6];
  #pragma unroll
  for (int a = 0; a < 4; a++)
    #pragma unroll
    for (int b = 0; b < 6; b++) acc[a][b] = (f32x4){0.f, 0.f, 0.f, 0.f};

  #define STAGE_A(kt, buf)                                                          \
    {                                                                               \
      const short* s0_ = A + (m0 + w * 16 + srow) * K + (kt) * 64 + scol;           \
      char* d_ = lds + (buf) * 65536 + (w * 16) * 128;                              \
      GLD16(s0_, d_);                                                               \
      GLD16(s0_ + 8LL * K, d_ + 1024);                                              \
    }
  #define STAGE_B(h, kt, buf)                                                       \
    {                                                                               \
      const short* s0_ = W + (n0 + (h) * 128 + w * 16 + srow) * K + (kt) * 64 + scol; \
      char* d_ = lds + (buf) * 65536 + 16384 + (h) * 16384 + (w * 16) * 128;        \
      GLD16(s0_, d_);                                                               \
      GLD16(s0_ + 8LL * K, d_ + 1024);                                              \
    }

  #define RDA(buf, fmL, k) (*reinterpret_cast<const bf16x8*>(                       \
      lds + (buf) * 65536 + ((wm * 64 + (fmL) * 16 + l16) * 128) +                  \
      ((((k) * 64 + g * 16)) ^ csw)))
  #define RDB(buf, h, j, k) (*reinterpret_cast<const bf16x8*>(                      \
      lds + (buf) * 65536 + 16384 + (h) * 16384 +                                   \
      ((wn * 16 + (j) * 64 + l16) * 128) + ((((k) * 64 + g * 16)) ^ csw)))

  STAGE_A(0, 0);
  STAGE_B(0, 0, 0);
  STAGE_B(1, 0, 0);
  STAGE_B(2, 0, 0);
  WAITVM(4);
  BARRIER();

  bf16x8 af[4][2], bfr[2][2];
  for (int kt = 0; kt < 32; ++kt) {
    const int cur = kt & 1, nxt = cur ^ 1;
    const int ks = (kt + 1 < 32) ? (kt + 1) : kt;

    // ---- P0 ----
    #pragma unroll
    for (int fm = 0; fm < 4; fm++)
      #pragma unroll
      for (int k = 0; k < 2; k++) af[fm][k] = RDA(cur, fm, k);
    #pragma unroll
    for (int j = 0; j < 2; j++)
      #pragma unroll
      for (int k = 0; k < 2; k++) bfr[j][k] = RDB(cur, 0, j, k);
    STAGE_A(ks, nxt);
    STAGE_B(0, ks, nxt);
    WAITVM(6);
    BARRIER();
    __builtin_amdgcn_s_setprio(1);
    #pragma unroll
    for (int fm = 0; fm < 4; fm++)
      #pragma unroll
      for (int j = 0; j < 2; j++)
        #pragma unroll
        for (int k = 0; k < 2; k++)
          acc[fm][j] = __builtin_amdgcn_mfma_f32_16x16x32_bf16(af[fm][k], bfr[j][k], acc[fm][j], 0, 0, 0);
    __builtin_amdgcn_s_setprio(0);
    BARRIER();

    // ---- P1 ----
    #pragma unroll
    for (int j = 0; j < 2; j++)
      #pragma unroll
      for (int k = 0; k < 2; k++) bfr[j][k] = RDB(cur, 1, j, k);
    STAGE_B(1, ks, nxt);
    WAITVM(6);
    BARRIER();
    __builtin_amdgcn_s_setprio(1);
    #pragma unroll
    for (int fm = 0; fm < 4; fm++)
      #pragma unroll
      for (int j = 0; j < 2; j++)
        #pragma unroll
        for (int k = 0; k < 2; k++)
          acc[fm][2 + j] = __builtin_amdgcn_mfma_f32_16x16x32_bf16(af[fm][k], bfr[j][k], acc[fm][2 + j], 0, 0, 0);
    __builtin_amdgcn_s_setprio(0);
    BARRIER();

    // ---- P2 ----
    #pragma unroll
    for (int j = 0; j < 2; j++)
      #pragma unroll
      for (int k = 0; k < 2; k++) bfr[j][k] = RDB(cur, 2, j, k);
    STAGE_B(2, ks, nxt);
    WAITVM(4);
    BARRIER();
    __builtin_amdgcn_s_setprio(1);
    #pragma unroll
    for (int fm = 0; fm < 4; fm++)
      #pragma unroll
      for (int j = 0; j < 2; j++)
        #pragma unroll
        for (int k = 0; k < 2; k++)
          acc[fm][4 + j] = __builtin_amdgcn_mfma_f32_16x16x32_bf16(af[fm][k], bfr[j][k], acc[fm][4 + j], 0, 0, 0);
    __builtin_amdgcn_s_setprio(0);
    BARRIER();
  }

  #pragma unroll
  for (int fm = 0; fm < 4; fm++)
    #pragma unroll
    for (int fj = 0; fj < 6; fj++) {
      const long row0 = m0 + wm * 64 + fm * 16 + g * 4;
      const long col  = n0 + fj * 64 + wn * 16 + l16;
      if (col < 2048) {
        #pragma unroll
        for (int i = 0; i < 4; i++) Qo[(row0 + i) * 2048 + col] = f2bf(acc[fm][fj][i] * QSC);
      } else if (col < 4096) {
        #pragma unroll
        for (int i = 0; i < 4; i++) Ko[(row0 + i) * 2048 + (col - 2048)] = f2bf(acc[fm][fj][i]);
      } else {
        const long c2 = col - 4096;
        const long base = (((row0 >> 11) * 16 + (c2 >> 7)) * 128 + (c2 & 127)) * 2048 + (row0 & 2047);
        short4v pk;
        #pragma unroll
        for (int i = 0; i < 4; i++) pk[i] = f2bf(acc[fm][fj][i]);
        *reinterpret_cast<short4v*>(Vt + base) = pk;
      }
    }
  #undef STAGE_A
  #undef STAGE_B
  #undef RDA
  #undef RDB
}

// ---------------- out-proj GEMM: 128x256 tile, BK=64, 2-phase counted-vmcnt ----------------
// C[4096,2048] (fp32) = Z[4096,2048] * Wo[2048,2048]^T. Grid 256 = exactly 1 round.
// Race proof (FIFO): prologue stages {A,H0,H1}(6), vmcnt(2) retires {A,H0}.
// P0 reads {A,H0}, stages {A,H0}'(4) -> outstanding H1(2)+{A,H0}'(4)=6, vmcnt(4)
// retires H1 (1 phase+barrier before P1's read). P1 reads H1, stages H1'(2) ->
// outstanding {A,H0}'(4)+H1'(2)=6, vmcnt(2) retires {A,H0}' (ready for next P0).
// Same swizzle involution as gemm_qkv8.
__global__ __launch_bounds__(512, 2) void gemm_o2(const short* __restrict__ A,
                                                  const short* __restrict__ W,
                                                  float* __restrict__ C) {
  __shared__ __align__(1024) char lds[98304];   // 2 buf x (A 16KB + B 32KB)
  const int tid  = threadIdx.x;
  const int lane = tid & 63;
  const int w    = tid >> 6;
  const int wm   = w >> 2, wn = w & 3;   // wave tile 64 x 64
  const int l16  = lane & 15, g = lane >> 4;
  const int K    = 2048;

  int id = (int)blockIdx.x;
  id = (id & 7) * 32 + (id >> 3);        // XCD chunk map (256 % 8 == 0)
  const int mb = id & 31, nb = id >> 5;  // 32 M-blocks, 8 N-blocks
  const long m0 = (long)mb * 128, n0 = (long)nb * 256;

  const int srow = lane >> 3;
  const int scol = ((lane & 7) ^ srow) * 8;
  const int csw  = (l16 & 7) << 4;

  f32x4 acc[4][4];
  #pragma unroll
  for (int a = 0; a < 4; a++)
    #pragma unroll
    for (int b = 0; b < 4; b++) acc[a][b] = (f32x4){0.f, 0.f, 0.f, 0.f};

  #define OSTAGE_A(kt, buf)                                                         \
    {                                                                               \
      const short* s0_ = A + (m0 + w * 16 + srow) * K + (kt) * 64 + scol;           \
      char* d_ = lds + (buf) * 49152 + (w * 16) * 128;                              \
      GLD16(s0_, d_);                                                               \
      GLD16(s0_ + 8LL * K, d_ + 1024);                                              \
    }
  #define OSTAGE_B(h, kt, buf)                                                      \
    {                                                                               \
      const short* s0_ = W + (n0 + (h) * 128 + w * 16 + srow) * K + (kt) * 64 + scol; \
      char* d_ = lds + (buf) * 49152 + 16384 + (h) * 16384 + (w * 16) * 128;        \
      GLD16(s0_, d_);                                                               \
      GLD16(s0_ + 8LL * K, d_ + 1024);                                              \
    }
  #define ORDA(buf, fmL, k) (*reinterpret_cast<const bf16x8*>(                      \
      lds + (buf) * 49152 + ((wm * 64 + (fmL) * 16 + l16) * 128) +                  \
      ((((k) * 64 + g * 16)) ^ csw)))
  #define ORDB(buf, h, j, k) (*reinterpret_cast<const bf16x8*>(                     \
      lds + (buf) * 49152 + 16384 + (h) * 16384 +                                   \
      ((wn * 16 + (j) * 64 + l16) * 128) + ((((k) * 64 + g * 16)) ^ csw)))

  OSTAGE_A(0, 0);
  OSTAGE_B(0, 0, 0);
  OSTAGE_B(1, 0, 0);
  WAITVM(2);
  BARRIER();

  bf16x8 af[4][2], bfr[2][2];
  for (int kt = 0; kt < 32; ++kt) {
    const int cur = kt & 1, nxt = cur ^ 1;
    const int ks = (kt + 1 < 32) ? (kt + 1) : kt;

    // ---- P0: A x B-H0 (acc fn 0,1) ----
    #pragma unroll
    for (int fm = 0; fm < 4; fm++)
      #pragma unroll
      for (int k = 0; k < 2; k++) af[fm][k] = ORDA(cur, fm, k);
    #pragma unroll
    for (int j = 0; j < 2; j++)
      #pragma unroll
      for (int k = 0; k < 2; k++) bfr[j][k] = ORDB(cur, 0, j, k);
    OSTAGE_A(ks, nxt);
    OSTAGE_B(0, ks, nxt);
    WAITVM(4);
    BARRIER();
    __builtin_amdgcn_s_setprio(1);
    #pragma unroll
    for (int fm = 0; fm < 4; fm++)
      #pragma unroll
      for (int j = 0; j < 2; j++)
        #pragma unroll
        for (int k = 0; k < 2; k++)
          acc[fm][j] = __builtin_amdgcn_mfma_f32_16x16x32_bf16(af[fm][k], bfr[j][k], acc[fm][j], 0, 0, 0);
    __builtin_amdgcn_s_setprio(0);
    BARRIER();

    // ---- P1: A x B-H1 (acc fn 2,3) ----
    #pragma unroll
    for (int j = 0; j < 2; j++)
      #pragma unroll
      for (int k = 0; k < 2; k++) bfr[j][k] = ORDB(cur, 1, j, k);
    OSTAGE_B(1, ks, nxt);
    WAITVM(2);
    BARRIER();
    __builtin_amdgcn_s_setprio(1);
    #pragma unroll
    for (int fm = 0; fm < 4; fm++)
      #pragma unroll
      for (int j = 0; j < 2; j++)
        #pragma unroll
        for (int k = 0; k < 2; k++)
          acc[fm][2 + j] = __builtin_amdgcn_mfma_f32_16x16x32_bf16(af[fm][k], bfr[j][k], acc[fm][2 + j], 0, 0, 0);
    __builtin_amdgcn_s_setprio(0);
    BARRIER();
  }

  // epilogue: row = m0 + wm*64 + fm*16 + g*4, col = n0 + (fn>>1)*128 + (fn&1)*64 + wn*16 + l16
  #pragma unroll
  for (int fm = 0; fm < 4; fm++)
    #pragma unroll
    for (int fn = 0; fn < 4; fn++) {
      const long row0 = m0 + wm * 64 + fm * 16 + g * 4;
      const long col  = n0 + (fn >> 1) * 128 + (fn & 1) * 64 + wn * 16 + l16;
      #pragma unroll
      for (int i = 0; i < 4; i++) C[(row0 + i) * 2048 + col] = acc[fm][fn][i];
    }
  #undef OSTAGE_A
  #undef OSTAGE_B
  #undef ORDA
  #undef ORDB
}

// ---------------- flash attention v6: QBLK=128 (32 q/wave), KVBLK=64 ----------------
// Q pre-scaled; exp2 softmax w/ per-lane slack fast path; K/V staged via
// reg-prefetch (T14); wave-uniform skip of fully-masked tail tiles.
__global__ __launch_bounds__(256, 2) void attn_kernel(const short* __restrict__ Q,
                                                      const short* __restrict__ K,
                                                      const short* __restrict__ Vt,
                                                      short* __restrict__ Z) {
  __shared__ short Ks[64][136];
  __shared__ short Vs[128][72];
  __shared__ short plds[4][32][72];

  const int tid  = threadIdx.x;
  const int lane = tid & 63;
  const int w    = tid >> 6;
  const int l16  = lane & 15, g = lane >> 4;

  const int bh = blockIdx.x;              // 0..31
  const int bx = 15 - (int)blockIdx.y;    // heavy blocks dispatch first (LPT)
  const int b  = bh >> 4, h = bh & 15;
  const int q0 = bx * 128;

  const float LOG2E  = 1.4426950408889634f;
  const float slope2 = exp2f(-0.5f * (float)(h + 1)) * LOG2E;
  const float CLAMP2 = 1477.3197f;   // 1024*log2e

  bf16x8 qf[2][4];
  #pragma unroll
  for (int mi = 0; mi < 2; mi++) {
    const long qoff = ((long)(b * 2048 + q0 + w * 32 + mi * 16 + l16)) * 2048 + h * 128;
    #pragma unroll
    for (int c = 0; c < 4; c++)
      qf[mi][c] = *reinterpret_cast<const bf16x8*>(Q + qoff + c * 32 + g * 8);
  }

  const f32x4 zero4 = {0.f, 0.f, 0.f, 0.f};
  f32x4 zacc[2][8];
  #pragma unroll
  for (int mi = 0; mi < 2; mi++)
    #pragma unroll
    for (int s = 0; s < 8; s++) zacc[mi][s] = zero4;
  float m2[2][4], li[2][4];
  #pragma unroll
  for (int mi = 0; mi < 2; mi++)
    #pragma unroll
    for (int i = 0; i < 4; i++) { m2[mi][i] = -3e38f; li[mi][i] = 0.f; }

  float aj[4];
  #pragma unroll
  for (int ni = 0; ni < 4; ni++) aj[ni] = slope2 * (float)(ni * 16 + l16);

  const int krow = tid >> 4, kcol = (tid & 15) * 8;
  const int vrow = tid >> 3, vcol = (tid & 7) * 8;
  const short* Kh = K + ((long)b * 2048) * 2048 + h * 128;
  const short* Vh = Vt + ((long)(b * 16 + h) * 128) * 2048;

  bf16x8 kreg[4], vreg[4];
  #pragma unroll
  for (int j = 0; j < 4; j++)
    kreg[j] = *reinterpret_cast<const bf16x8*>(Kh + (long)(j * 16 + krow) * 2048 + kcol);
  #pragma unroll
  for (int j = 0; j < 4; j++)
    vreg[j] = *reinterpret_cast<const bf16x8*>(Vh + (long)(j * 32 + vrow) * 2048 + vcol);

  const int ntiles = 2 * bx + 2;
  for (int t = 0; t < ntiles; t++) {
    const int kv0 = t * 64;
    __syncthreads();
    #pragma unroll
    for (int j = 0; j < 4; j++)
      *reinterpret_cast<bf16x8*>(&Ks[j * 16 + krow][kcol]) = kreg[j];
    #pragma unroll
    for (int j = 0; j < 4; j++)
      *reinterpret_cast<bf16x8*>(&Vs[j * 32 + vrow][vcol]) = vreg[j];
    __syncthreads();

    const bool active = (q0 + w * 32 + 31) >= kv0;   // wave-uniform
    f32x4 sc[2][4];
    if (active) {
      #pragma unroll
      for (int mi = 0; mi < 2; mi++)
        #pragma unroll
        for (int ni = 0; ni < 4; ni++) sc[mi][ni] = zero4;
      #pragma unroll
      for (int ni = 0; ni < 4; ni++)
        #pragma unroll
        for (int kc = 0; kc < 4; kc++) {
          const bf16x8 kf = *reinterpret_cast<const bf16x8*>(&Ks[ni * 16 + l16][kc * 32 + g * 8]);
          #pragma unroll
          for (int mi = 0; mi < 2; mi++)
            sc[mi][ni] = __builtin_amdgcn_mfma_f32_16x16x32_bf16(qf[mi][kc], kf, sc[mi][ni], 0, 0, 0);
        }
    }

    if (t + 1 < ntiles) {
      const short* kb = Kh + (long)(kv0 + 64) * 2048;
      const short* vb = Vh + kv0 + 64;
      #pragma unroll
      for (int j = 0; j < 4; j++)
        kreg[j] = *reinterpret_cast<const bf16x8*>(kb + (long)(j * 16 + krow) * 2048 + kcol);
      #pragma unroll
      for (int j = 0; j < 4; j++)
        vreg[j] = *reinterpret_cast<const bf16x8*>(vb + (long)(j * 32 + vrow) * 2048 + vcol);
    }

    if (active) {
      const float bk = slope2 * (float)kv0;
      float bn[4];
      #pragma unroll
      for (int ni = 0; ni < 4; ni++) bn[ni] = bk + aj[ni];
      float rmax[2][4];
      float slack = -3e38f;
      #pragma unroll
      for (int mi = 0; mi < 2; mi++)
        #pragma unroll
        for (int i = 0; i < 4; i++) {
          const int qi = q0 + w * 32 + mi * 16 + g * 4 + i;
          float mx = -3e38f;
          #pragma unroll
          for (int ni = 0; ni < 4; ni++) {
            const int j = kv0 + ni * 16 + l16;
            float v = fminf(fmaxf(sc[mi][ni][i], -CLAMP2), CLAMP2) + bn[ni];
            v = (j <= qi) ? v : -3e38f;
            sc[mi][ni][i] = v;
            mx = fmaxf(mx, v);
          }
          rmax[mi][i] = mx;
          slack = fmaxf(slack, mx - m2[mi][i]);
        }
      if (__any(slack > 10.f)) {
        #pragma unroll
        for (int mi = 0; mi < 2; mi++)
          #pragma unroll
          for (int i = 0; i < 4; i++) {
            float bb = rmax[mi][i];
            #pragma unroll
            for (int ms = 1; ms < 16; ms <<= 1) bb = fmaxf(bb, __shfl_xor(bb, ms));
            const float mnew = fmaxf(m2[mi][i], bb);
            const float corr = fexp2(m2[mi][i] - mnew);
            m2[mi][i] = mnew;
            li[mi][i] *= corr;
            #pragma unroll
            for (int s = 0; s < 8; s++) zacc[mi][s][i] *= corr;
          }
      }
      #pragma unroll
      for (int mi = 0; mi < 2; mi++)
        #pragma unroll
        for (int i = 0; i < 4; i++) {
          float psum = 0.f;
          #pragma unroll
          for (int ni = 0; ni < 4; ni++) {
            const float p = fexp2(sc[mi][ni][i] - m2[mi][i]);
            plds[w][mi * 16 + g * 4 + i][ni * 16 + l16] = f2bf(p);
            psum += p;
          }
          li[mi][i] += psum;
        }

      bf16x8 paf[2][2];
      #pragma unroll
      for (int mi = 0; mi < 2; mi++)
        #pragma unroll
        for (int kk = 0; kk < 2; kk++)
          paf[mi][kk] = *reinterpret_cast<const bf16x8*>(&plds[w][mi * 16 + l16][kk * 32 + g * 8]);
      #pragma unroll
      for (int s = 0; s < 8; s++) {
        const bf16x8 vf0 = *reinterpret_cast<const bf16x8*>(&Vs[s * 16 + l16][g * 8]);
        const bf16x8 vf1 = *reinterpret_cast<const bf16x8*>(&Vs[s * 16 + l16][32 + g * 8]);
        #pragma unroll
        for (int mi = 0; mi < 2; mi++) {
          zacc[mi][s] = __builtin_amdgcn_mfma_f32_16x16x32_bf16(paf[mi][0], vf0, zacc[mi][s], 0, 0, 0);
          zacc[mi][s] = __builtin_amdgcn_mfma_f32_16x16x32_bf16(paf[mi][1], vf1, zacc[mi][s], 0, 0, 0);
        }
      }
    }
  }

  #pragma unroll
  for (int mi = 0; mi < 2; mi++)
    #pragma unroll
    for (int i = 0; i < 4; i++) {
      float s = li[mi][i];
      #pragma unroll
      for (int ms = 1; ms < 16; ms <<= 1) s += __shfl_xor(s, ms);
      li[mi][i] = s;
    }
  #pragma unroll
  for (int mi = 0; mi < 2; mi++)
    #pragma unroll
    for (int s = 0; s < 8; s++)
      #pragma unroll
      for (int i = 0; i < 4; i++) {
        const int qi = q0 + w * 32 + mi * 16 + g * 4 + i;
        const float zv = zacc[mi][s][i] / li[mi][i];
        Z[((long)(b * 2048 + qi)) * 2048 + h * 128 + s * 16 + l16] = f2bf(zv);
      }
}

// ---------------- launch ----------------
extern "C" void kernel_launch(void* const* d_in, const int* in_sizes, int n_in,
                              void* d_out, int out_size, void* d_ws, size_t ws_size,
                              hipStream_t stream) {
  const float* X  = (const float*)d_in[0];
  const float* Wq = (const float*)d_in[1];
  const float* Wk = (const float*)d_in[2];
  const float* Wv = (const float*)d_in[3];
  const float* Wo = (const float*)d_in[4];
  float* out = (float*)d_out;

  short* ws    = (short*)d_ws;
  short* Xb    = ws;                     // 8,388,608
  short* Wqkvb = ws + 8388608;           // 12,582,912 (Wq|Wk|Wv rows)
  short* Wob   = ws + 20971520;          // 4,194,304
  short* Qb    = ws + 25165824;          // 8,388,608
  short* Kb    = ws + 33554432;          // 8,388,608
  short* Vtb   = ws + 41943040;          // 8,388,608
  short* Zb    = Xb;

  cast_kernel<<<8192, 256, 0, stream>>>(X, Xb, 2097152);
  dim3 gw(4096, 4);
  cast_w_kernel<<<gw, 256, 0, stream>>>(Wq, Wk, Wv, Wo, Wqkvb, Wob);

  gemm_qkv8<<<512, 512, 0, stream>>>(Xb, Wqkvb, Qb, Kb, Vtb);

  dim3 ga(32, 16);   // x = head (bh), y = q-slot; bx = 15 - y (heavy first)
  attn_kernel<<<ga, 256, 0, stream>>>(Qb, Kb, Vtb, Zb);

  gemm_o2<<<256, 512, 0, stream>>>(Zb, Wob, out);
}